// Round 19
// baseline (331.475 us; speedup 1.0000x reference)
//
#include <hip/hip_runtime.h>
#include <hip/hip_bf16.h>
#include <math.h>

typedef __attribute__((ext_vector_type(8))) short short8;
typedef __attribute__((ext_vector_type(16))) float f32x16;

__device__ __forceinline__ float lrelu(float x){ return x >= 0.f ? x : 0.1f*x; }
__device__ __forceinline__ float sigmoidf(float x){ return 1.f/(1.f+expf(-x)); }
__device__ __forceinline__ short f2bf(float f){
  __hip_bfloat16 hb = __float2bfloat16(f);
  return *reinterpret_cast<short*>(&hb);
}
__device__ __forceinline__ float bf16f(short s){
  return __uint_as_float(((unsigned)(unsigned short)s)<<16);
}

// WFrag frag index: (((w*2+part)*2+mt)*4+kt)*512 + lane*8
// w: 0=Wq 1=Wk 2=Wo (mt=0,1) | 3=Wv[0:32] 4=Wv[32:64] 5=WriE|WrcE (mt=0 only)
__device__ __forceinline__ int WFofs(int w,int part,int mt,int kt){
  return (((w*2+part)*2+mt)*4+kt)*512;
}

// ---------- K0: effective weights WriE = Wri@Wv, WrcE = Wrc@Wv, biases ----------
__global__ void k0_combine(const float* __restrict__ Wv, const float* __restrict__ bv,
                           const float* __restrict__ Wri, const float* __restrict__ bri,
                           const float* __restrict__ Wrc, const float* __restrict__ brc,
                           float* __restrict__ WriE, float* __restrict__ briE,
                           float* __restrict__ WrcE, float* __restrict__ brcE){
  int idx = blockIdx.x*256 + threadIdx.x;
  if (idx < 1024){
    int j = idx>>6, c = idx&63;
    float s1=0.f, s2=0.f;
    for (int k=0;k<64;k++){ s1 = fmaf(Wri[j*64+k], Wv[k*64+c], s1); s2 = fmaf(Wrc[j*64+k], Wv[k*64+c], s2); }
    WriE[idx]=s1; WrcE[idx]=s2;
  }
  if (idx < 16){
    float s1=bri[idx], s2=brc[idx];
    for (int k=0;k<64;k++){ s1 = fmaf(Wri[idx*64+k], bv[k], s1); s2 = fmaf(Wrc[idx*64+k], bv[k], s2); }
    briE[idx]=s1; brcE[idx]=s2;
  }
}

// ---------- prep: MFMA W-frag blob (Wq/Wk/Wo/Wv/Wri|Wrc, hi/lo) ----------
__global__ void k_prep(const float* __restrict__ Wq, const float* __restrict__ Wk,
                       const float* __restrict__ Wo, const float* __restrict__ Wv,
                       const float* __restrict__ WriE, const float* __restrict__ WrcE,
                       short* __restrict__ WFrag){
  int idx = blockIdx.x*256 + threadIdx.x;
  if (idx < 6144){
    int w = idx>>10, rem = idx&1023;
    int part = rem>>9, mt = (rem>>8)&1, kt = (rem>>6)&3, lane = rem&63;
    int hh = lane>>5;
    short8 frag;
    #pragma unroll
    for (int i=0;i<8;i++){
      int kl = (hh<<2) + (i&3) + ((i>>2)<<3);
      int kfull = (kt<<4) + kl;
      float val = 0.f;
      if (w < 3){
        const float* W = (w==0)?Wq:((w==1)?Wk:Wo);
        int j = (mt<<5)|(lane&31);
        val = W[j*64 + kfull];
      } else if (mt == 0){
        int j = lane&31;
        if (w==3)      val = Wv[j*64 + kfull];
        else if (w==4) val = Wv[(32+j)*64 + kfull];
        else           val = (j<16) ? WriE[j*64 + kfull] : WrcE[(j-16)*64 + kfull];
      }
      short hi = f2bf(val);
      frag[i] = part ? f2bf(val - bf16f(hi)) : hi;
    }
    *(short8*)&WFrag[WFofs(w,part,mt,kt) + (lane<<3)] = frag;
  }
}

// ---------- premask 1 ----------
__global__ void k_premask1(const float* __restrict__ Wm1, const float* __restrict__ bm1,
                           float* __restrict__ mrow1, float* __restrict__ mrow0){
  __shared__ float red[256];
  int j = blockIdx.x, tid = threadIdx.x;
  const float* row = Wm1 + (size_t)j*4096;
  float s=0.f;
  for (int e=tid;e<4096;e+=256) s += row[e];
  red[tid]=s; __syncthreads();
  for (int o=128;o;o>>=1){ if (tid<o) red[tid]+=red[tid+o]; __syncthreads(); }
  if (tid==0){
    float t = red[0]+bm1[j];
    mrow1[j] = lrelu(t);
    mrow0[j] = lrelu(bm1[j]);
  }
}

// ---------- premask 2 (+ transposed copies) ----------
__global__ void k_premask2(const float* __restrict__ Wm2, const float* __restrict__ bm2,
                           const float* __restrict__ mrow1, const float* __restrict__ mrow0,
                           float* __restrict__ mask1, float* __restrict__ mask0,
                           float* __restrict__ mask1T, float* __restrict__ mask0T){
  __shared__ float r1[256], r0[256];
  int e = blockIdx.x, tid = threadIdx.x;
  const float* row = Wm2 + (size_t)e*2048;
  float s1=0.f, s0=0.f;
  for (int j=tid;j<2048;j+=256){ float wv=row[j]; s1 = fmaf(wv, mrow1[j], s1); s0 = fmaf(wv, mrow0[j], s0); }
  r1[tid]=s1; r0[tid]=s0; __syncthreads();
  for (int o=128;o;o>>=1){ if (tid<o){ r1[tid]+=r1[tid+o]; r0[tid]+=r0[tid+o]; } __syncthreads(); }
  if (tid==0){
    float m1 = r1[0]+bm2[e], m0 = r0[0]+bm2[e];
    mask1[e]=m1; mask0[e]=m0;
    int p = e>>6, c = e&63;
    mask1T[(c<<6)|p]=m1; mask0T[(c<<6)|p]=m0;
  }
}

// ---------- K1 (MFMA): per-pixel v, xm, x_, block channel-sums (+T5 setprio) ----------
__global__ __launch_bounds__(256, 4) void k1_pw(
    const float* __restrict__ x, const short* __restrict__ WFrag,
    const float* __restrict__ bv,
    const float* __restrict__ briE, const float* __restrict__ brcE,
    const float* __restrict__ ln_w, const float* __restrict__ ln_b,
    float* __restrict__ v, float* __restrict__ x_, float* __restrict__ xm,
    float* __restrict__ bsum){
  __shared__ float wred[4][16];
  int tid = threadIdx.x, lane = tid&63, wvi = tid>>6, l31 = lane&31, h = lane>>5;
  int blk = blockIdx.x;
  int b = blk>>9;
  int hw = ((blk&511)<<7) | (wvi<<5) | l31;
  size_t xb = (((size_t)b)<<22) + hw;
  short8 XH[4], XL[4];
  #pragma unroll
  for (int kt=0;kt<4;kt++){
    float xv[8];
    #pragma unroll
    for (int i=0;i<8;i++){
      int c = (kt<<4) + (h<<2) + (i&3) + ((i>>2)<<3);
      xv[i] = x[xb + ((size_t)c<<16)];
    }
    short8 fh, fl;
    #pragma unroll
    for (int i=0;i<8;i++){ short hi=f2bf(xv[i]); fh[i]=hi; fl[i]=f2bf(xv[i]-bf16f(hi)); }
    XH[kt]=fh; XL[kt]=fl;
  }
  f32x16 T[3];
  #pragma unroll
  for (int t3=0;t3<3;t3++){
    f32x16 acc;
    #pragma unroll
    for (int r=0;r<16;r++) acc[r]=0.f;
    __builtin_amdgcn_s_setprio(1);
    #pragma unroll
    for (int kt=0;kt<4;kt++){
      short8 WAh = *(const short8*)&WFrag[WFofs(3+t3,0,0,kt) + (lane<<3)];
      short8 WAl = *(const short8*)&WFrag[WFofs(3+t3,1,0,kt) + (lane<<3)];
      acc = __builtin_amdgcn_mfma_f32_32x32x16_bf16(WAh, XH[kt], acc, 0,0,0);
      acc = __builtin_amdgcn_mfma_f32_32x32x16_bf16(WAh, XL[kt], acc, 0,0,0);
      acc = __builtin_amdgcn_mfma_f32_32x32x16_bf16(WAl, XH[kt], acc, 0,0,0);
    }
    __builtin_amdgcn_s_setprio(0);
    T[t3]=acc;
  }
  #pragma unroll
  for (int r=0;r<16;r++){
    int c0 = (r&3) + ((r>>2)<<3) + (h<<2);
    v[xb + ((size_t)c0<<16)]      = T[0][r] + bv[c0];
    v[xb + ((size_t)(c0+32)<<16)] = T[1][r] + bv[c0+32];
  }
  float s1 = 0.f;
  #pragma unroll
  for (int r=0;r<8;r++){
    int j = (r&3) + ((r>>2)<<3) + (h<<2);
    s1 += lrelu(T[2][r] + briE[j]);
  }
  s1 += __shfl_xor(s1, 32);
  xm[(((size_t)b)<<16) + hw] = s1*(1.f/16.f);
  float vals[8], u = 0.f;
  #pragma unroll
  for (int r=0;r<8;r++){
    int j = (r&3) + ((r>>2)<<3) + (h<<2);
    float t = T[2][8+r] + brcE[j];
    vals[r]=t; u += t;
  }
  u += __shfl_xor(u, 32);
  u *= (1.f/16.f);
  float s2 = 0.f;
  #pragma unroll
  for (int r=0;r<8;r++){ float d = vals[r]-u; s2 += d*d; }
  s2 += __shfl_xor(s2, 32);
  float inv = 1.0f / sqrtf(s2*(1.f/16.f) + 1e-6f);
  float bs[8];
  #pragma unroll
  for (int r=0;r<8;r++){
    int j = (r&3) + ((r>>2)<<3) + (h<<2);
    float t = lrelu((vals[r]-u)*inv*ln_w[j] + ln_b[j]);
    x_[(((size_t)(b*16+j))<<16) + hw] = t;
    bs[r]=t;
  }
  #pragma unroll
  for (int r=0;r<8;r++){
    float val = bs[r];
    val += __shfl_xor(val,1); val += __shfl_xor(val,2); val += __shfl_xor(val,4);
    val += __shfl_xor(val,8); val += __shfl_xor(val,16);
    bs[r]=val;
  }
  if (l31==0){
    #pragma unroll
    for (int r=0;r<8;r++){
      int j = (r&3) + ((r>>2)<<3) + (h<<2);
      wred[wvi][j] = bs[r];
    }
  }
  __syncthreads();
  if (tid<16) bsum[blk*16+tid] = wred[0][tid]+wred[1][tid]+wred[2][tid]+wred[3][tid];
}

// ---------- K2: sa (LDS-tiled 16ch x 18x18) ----------
__global__ __launch_bounds__(256) void k2_sa(const float* __restrict__ x_,
    const float* __restrict__ Wsa, const float* __restrict__ bsa, float* __restrict__ sa){
  __shared__ float T[16*324];
  int blk = blockIdx.x;
  int b = blk>>8;
  int tile = blk&255;
  int x0 = (tile&15)<<4, y0 = (tile>>4)<<4;
  int tid = threadIdx.x;
  for (int e=tid; e<5184; e+=256){
    int ch = e/324, rem = e-ch*324, r = rem/18, cc = rem-r*18;
    int y = y0+r-1, xx = x0+cc-1;
    float v = 0.f;
    if ((unsigned)y<256u && (unsigned)xx<256u) v = x_[(((size_t)(b*16+ch))<<16)+(y<<8)+xx];
    T[e] = v;
  }
  __syncthreads();
  int px = tid&15, py = tid>>4;
  float acc = bsa[0];
  #pragma unroll
  for (int ch=0; ch<16; ch++){
    const float* Tc = T + ch*324 + py*18 + px;
    #pragma unroll
    for (int ky=0;ky<3;ky++)
      #pragma unroll
      for (int kx=0;kx<3;kx++)
        acc = fmaf(Wsa[ch*9+ky*3+kx], Tc[ky*18+kx], acc);
  }
  sa[(((size_t)b)<<16) + ((y0+py)<<8) + x0+px] = sigmoidf(acc);
}

// ---------- K3: ca ----------
__global__ void k3_ca(const float* __restrict__ bsum, const float* __restrict__ Wca,
                      const float* __restrict__ bca, float* __restrict__ ca){
  __shared__ float meanx[4][16];
  int tid = threadIdx.x;
  if (tid < 64){
    int b = tid>>4, j = tid&15;
    float s=0.f;
    for (int blk=0;blk<512;blk++) s += bsum[(b*512+blk)*16 + j];
    meanx[b][j] = s*(1.f/65536.f);
  }
  __syncthreads();
  int b = tid>>6, oc = tid&63;
  float a = bca[oc];
  #pragma unroll
  for (int j=0;j<16;j++) a = fmaf(Wca[oc*16+j], meanx[b][j], a);
  ca[tid] = sigmoidf(a);
}

// ---------- K4a: per-window variance ----------
__global__ void k4a_var(const float* __restrict__ xm, float* __restrict__ var){
  int t = blockIdx.x*256 + threadIdx.x;
  int b = t>>10, n = t&1023, wh = n>>5, ww = n&31;
  const float* base = xm + (((size_t)b)<<16) + (wh<<11) + (ww<<3);
  float s=0.f;
  #pragma unroll
  for (int dh=0;dh<8;dh++){
    #pragma unroll
    for (int dw=0;dw<8;dw++) s += base[(dh<<8)+dw];
  }
  float mean = s*(1.f/64.f);
  float ss=0.f;
  #pragma unroll
  for (int dh=0;dh<8;dh++){
    #pragma unroll
    for (int dw=0;dw<8;dw++){ float d = base[(dh<<8)+dw]-mean; ss += d*d; }
  }
  var[t] = ss*(1.f/63.f);
}

// ---------- K4b: rank -> sel ----------
__global__ __launch_bounds__(1024) void k4b_sel(const float* __restrict__ var, float* __restrict__ sel){
  __shared__ float vs[1024];
  int b = blockIdx.x, tid = threadIdx.x;
  float mine = var[b*1024+tid];
  vs[tid]=mine; __syncthreads();
  int rank=0;
  for (int j=0;j<1024;j++){
    float o = vs[j];
    rank += (o < mine) || (o == mine && j < tid);
  }
  sel[b*1024+tid] = (rank >= 512) ? 1.f : 0.f;
}

// ---------- K6: 2 waves per window, MFMA bf16 hi/lo, (256,3) + s_setprio (T5) ----------
__global__ __launch_bounds__(256, 3) void k6_attn(
    const float* __restrict__ x, const float* __restrict__ v, const float* __restrict__ sa,
    const float* __restrict__ sel,
    const float* __restrict__ mask1, const float* __restrict__ mask0,
    const float* __restrict__ mask1T, const float* __restrict__ mask0T,
    const short* __restrict__ WFrag,
    const float* __restrict__ bq, const float* __restrict__ bk,
    float* __restrict__ out){
  __shared__ short8 KAlds[2][2][8][64];   // [win][keyhalf][hi0-3|lo4-7][lane]
  int tid = threadIdx.x;
  int lane = tid & 63, wvi = tid >> 6;
  int wi = wvi >> 1, ht = wvi & 1;
  int l31 = lane & 31, h = lane >> 5;
  int bid = blockIdx.x;
  int blk = ((bid & 7) << 8) | (bid >> 3);      // 2048 = 8*256 bijective XCD swizzle
  int wg = (blk << 1) | wi;
  int b = wg >> 10, n = wg & 1023;
  int pix0 = ((n >> 5) << 11) | ((n & 31) << 3);
  bool sel1 = sel[wg] > 0.5f;
  const float* mrow  = sel1 ? mask1  : mask0;
  const float* mrowT = sel1 ? mask1T : mask0T;
  size_t cbase = (((size_t)b) << 22) + pix0;

  int p = (ht<<5) | l31;
  int po = ((p>>3)<<8) | (p&7);
  size_t gp = cbase + po;
  const float* mr = mrow + (p<<6);
  short8 XBh[4], XBl[4];
  #pragma unroll
  for (int kt=0;kt<4;kt++){
    float4 ma = *(const float4*)&mr[(kt<<4)+(h<<2)];
    float4 mb = *(const float4*)&mr[(kt<<4)+(h<<2)+8];
    float xv[8];
    #pragma unroll
    for (int i=0;i<8;i++){
      int c = (kt<<4) + (h<<2) + (i&3) + ((i>>2)<<3);
      xv[i] = x[gp + ((size_t)c<<16)];
    }
    xv[0]*=ma.x; xv[1]*=ma.y; xv[2]*=ma.z; xv[3]*=ma.w;
    xv[4]*=mb.x; xv[5]*=mb.y; xv[6]*=mb.z; xv[7]*=mb.w;
    short8 fh, fl;
    #pragma unroll
    for (int i=0;i<8;i++){
      short hi = f2bf(xv[i]); fh[i]=hi; fl[i]=f2bf(xv[i]-bf16f(hi));
    }
    XBh[kt]=fh; XBl[kt]=fl;
  }

  short8 QBh[4], QBl[4];
  #pragma unroll
  for (int mt=0;mt<2;mt++){
    f32x16 acc;
    #pragma unroll
    for (int r=0;r<16;r++) acc[r]=0.f;
    __builtin_amdgcn_s_setprio(1);
    #pragma unroll
    for (int kt=0;kt<4;kt++){
      short8 WAh = *(const short8*)&WFrag[WFofs(0,0,mt,kt) + (lane<<3)];
      short8 WAl = *(const short8*)&WFrag[WFofs(0,1,mt,kt) + (lane<<3)];
      acc = __builtin_amdgcn_mfma_f32_32x32x16_bf16(WAh, XBh[kt], acc, 0,0,0);
      acc = __builtin_amdgcn_mfma_f32_32x32x16_bf16(WAh, XBl[kt], acc, 0,0,0);
      acc = __builtin_amdgcn_mfma_f32_32x32x16_bf16(WAl, XBh[kt], acc, 0,0,0);
    }
    __builtin_amdgcn_s_setprio(0);
    #pragma unroll
    for (int rr=0;rr<4;rr++){
      float4 b4 = *(const float4*)&bq[(mt<<5)+(rr<<3)+(h<<2)];
      acc[4*rr+0]+=b4.x; acc[4*rr+1]+=b4.y; acc[4*rr+2]+=b4.z; acc[4*rr+3]+=b4.w;
    }
    #pragma unroll
    for (int kk=0;kk<2;kk++){
      short8 fh, fl;
      #pragma unroll
      for (int i=0;i<8;i++){
        float vv = acc[8*kk+i];
        short hi = f2bf(vv); fh[i]=hi; fl[i]=f2bf(vv-bf16f(hi));
      }
      QBh[2*mt+kk]=fh; QBl[2*mt+kk]=fl;
    }
  }

  #pragma unroll
  for (int mt=0;mt<2;mt++){
    f32x16 acc;
    #pragma unroll
    for (int r=0;r<16;r++) acc[r]=0.f;
    __builtin_amdgcn_s_setprio(1);
    #pragma unroll
    for (int kt=0;kt<4;kt++){
      short8 WAh = *(const short8*)&WFrag[WFofs(1,0,mt,kt) + (lane<<3)];
      short8 WAl = *(const short8*)&WFrag[WFofs(1,1,mt,kt) + (lane<<3)];
      acc = __builtin_amdgcn_mfma_f32_32x32x16_bf16(WAh, XBh[kt], acc, 0,0,0);
      acc = __builtin_amdgcn_mfma_f32_32x32x16_bf16(WAh, XBl[kt], acc, 0,0,0);
      acc = __builtin_amdgcn_mfma_f32_32x32x16_bf16(WAl, XBh[kt], acc, 0,0,0);
    }
    __builtin_amdgcn_s_setprio(0);
    #pragma unroll
    for (int rr=0;rr<4;rr++){
      float4 b4 = *(const float4*)&bk[(mt<<5)+(rr<<3)+(h<<2)];
      acc[4*rr+0]+=b4.x; acc[4*rr+1]+=b4.y; acc[4*rr+2]+=b4.z; acc[4*rr+3]+=b4.w;
    }
    #pragma unroll
    for (int kk=0;kk<2;kk++){
      short8 fh, fl;
      #pragma unroll
      for (int i=0;i<8;i++){
        float vv = acc[8*kk+i];
        short hi = f2bf(vv); fh[i]=hi; fl[i]=f2bf(vv-bf16f(hi));
      }
      KAlds[wi][ht][2*mt+kk][lane]   = fh;
      KAlds[wi][ht][4+2*mt+kk][lane] = fl;
    }
  }
  __syncthreads();

  f32x16 ST[2];
  #pragma unroll
  for (int mt=0;mt<2;mt++){
    f32x16 acc;
    #pragma unroll
    for (int r=0;r<16;r++) acc[r]=0.f;
    __builtin_amdgcn_s_setprio(1);
    #pragma unroll
    for (int kt=0;kt<4;kt++){
      short8 kh = KAlds[wi][mt][kt][lane];
      short8 kl = KAlds[wi][mt][4+kt][lane];
      acc = __builtin_amdgcn_mfma_f32_32x32x16_bf16(kh, QBh[kt], acc, 0,0,0);
      acc = __builtin_amdgcn_mfma_f32_32x32x16_bf16(kh, QBl[kt], acc, 0,0,0);
      acc = __builtin_amdgcn_mfma_f32_32x32x16_bf16(kl, QBh[kt], acc, 0,0,0);
    }
    __builtin_amdgcn_s_setprio(0);
    ST[mt] = acc;
  }

  float mx = ST[0][0];
  #pragma unroll
  for (int r=1;r<16;r++) mx = fmaxf(mx, ST[0][r]);
  #pragma unroll
  for (int r=0;r<16;r++) mx = fmaxf(mx, ST[1][r]);
  mx = fmaxf(mx, __shfl_xor(mx, 32));
  float sum = 0.f;
  #pragma unroll
  for (int mt=0;mt<2;mt++)
    #pragma unroll
    for (int r=0;r<16;r++){ float e = expf(ST[mt][r]-mx); ST[mt][r]=e; sum += e; }
  sum += __shfl_xor(sum, 32);
  float inv = 1.f/sum;

  short8 PB[4];
  #pragma unroll
  for (int mt=0;mt<2;mt++)
    #pragma unroll
    for (int kk=0;kk<2;kk++){
      short8 f;
      #pragma unroll
      for (int i=0;i<8;i++) f[i] = f2bf(ST[mt][8*kk+i]*inv);
      PB[2*mt+kk]=f;
    }

  float sav = sa[(((size_t)b)<<16) + pix0 + po];

  #pragma unroll
  for (int mtc=0;mtc<2;mtc++){
    int c0 = (mtc<<5);
    int cl = c0 | l31;
    const float* vp = v + cbase + ((size_t)cl<<16);
    const float* mTr = mrowT + (cl<<6);
    f32x16 acc;
    #pragma unroll
    for (int r=0;r<16;r++) acc[r]=0.f;
    __builtin_amdgcn_s_setprio(1);
    #pragma unroll
    for (int kt=0;kt<4;kt++){
      float4 va  = *(const float4*)&vp[((kt<<1)<<8) + (h<<2)];
      float4 vb2 = *(const float4*)&vp[(((kt<<1)|1)<<8) + (h<<2)];
      float4 ma = *(const float4*)&mTr[(kt<<4)+(h<<2)];
      float4 mb = *(const float4*)&mTr[(kt<<4)+(h<<2)+8];
      short8 f;
      f[0]=f2bf(va.x*ma.x); f[1]=f2bf(va.y*ma.y); f[2]=f2bf(va.z*ma.z); f[3]=f2bf(va.w*ma.w);
      f[4]=f2bf(vb2.x*mb.x); f[5]=f2bf(vb2.y*mb.y); f[6]=f2bf(vb2.z*mb.z); f[7]=f2bf(vb2.w*mb.w);
      acc = __builtin_amdgcn_mfma_f32_32x32x16_bf16(f, PB[kt], acc, 0,0,0);
    }
    __builtin_amdgcn_s_setprio(0);
    #pragma unroll
    for (int rr=0;rr<4;rr++){
      float4 m4 = *(const float4*)&mr[c0+(rr<<3)+(h<<2)];
      #pragma unroll
      for (int t=0;t<4;t++){
        int c = c0 + (rr<<3) + (h<<2) + t;
        size_t g = cbase + ((size_t)c<<16) + po;
        float vv = v[g];
        float mm = (t==0)?m4.x:(t==1)?m4.y:(t==2)?m4.z:m4.w;
        out[g] = acc[4*rr+t] + sav*vv*(1.f-mm);
      }
    }
  }
}

// ---------- K7: fused dw3x3(pad1) -> dw3x3(dil2,pad2) -> gelu*ca + residual (32x32 tiles) ----------
__global__ __launch_bounds__(256) void k7_fused(const float* __restrict__ in,
    const float* __restrict__ Wd1, const float* __restrict__ bd1,
    const float* __restrict__ Wd2, const float* __restrict__ bd2,
    const float* __restrict__ ca, float* __restrict__ dwout){
  __shared__ float IN[38*39];
  __shared__ float C1[36*37];
  int blk = blockIdx.x;
  int tile = blk & 63;
  int tx = tile & 7, ty = tile >> 3;
  int ch = (blk>>6) & 63, b = blk>>12;
  int x0 = tx<<5, y0 = ty<<5;
  const float* plane = in + (((size_t)(b*64+ch))<<16);
  int tid = threadIdx.x;
  for (int e = tid; e < 1444; e += 256){
    int r = e/38, cc = e - r*38;
    int y = y0 + r - 3, xx = x0 + cc - 3;
    float vv = 0.f;
    if ((unsigned)y < 256u && (unsigned)xx < 256u) vv = plane[(y<<8)+xx];
    IN[r*39+cc] = vv;
  }
  __syncthreads();
  float w1[9], w2[9];
  #pragma unroll
  for (int t=0;t<9;t++){ w1[t]=Wd1[ch*9+t]; w2[t]=Wd2[ch*9+t]; }
  float b1 = bd1[ch];
  for (int e = tid; e < 1296; e += 256){
    int r = e/36, cc = e - r*36;
    int yc1 = y0 + r - 2, xc1 = x0 + cc - 2;
    float acc = 0.f;
    if ((unsigned)yc1 < 256u && (unsigned)xc1 < 256u){
      acc = b1;
      #pragma unroll
      for (int ky=0;ky<3;ky++)
        #pragma unroll
        for (int kx=0;kx<3;kx++)
          acc = fmaf(w1[ky*3+kx], IN[(r+ky)*39 + cc+kx], acc);
    }
    C1[r*37+cc] = acc;
  }
  __syncthreads();
  int px = tid & 31, py0 = tid >> 5;
  float cav = ca[b*64+ch];
  float b2 = bd2[ch];
  #pragma unroll
  for (int q=0;q<4;q++){
    int py = py0 + (q<<3);
    float acc = b2;
    #pragma unroll
    for (int ky=0;ky<3;ky++)
      #pragma unroll
      for (int kx=0;kx<3;kx++)
        acc = fmaf(w2[ky*3+kx], C1[(py+2*ky)*37 + px+2*kx], acc);
    float g = 0.5f*acc*(1.f + erff(acc*0.70710678118654752f));
    float resid = IN[(py+3)*39 + px+3];
    size_t o = (((size_t)(b*64+ch))<<16) + ((size_t)((y0+py)<<8)) + x0+px;
    dwout[o] = fmaf(g, cav, resid);
  }
}

// ---------- K7c: final 1x1 conv via MFMA (hi/lo 3-product, +T5 setprio) ----------
__global__ __launch_bounds__(256, 3) void k7c_proj(const float* __restrict__ in,
    const short* __restrict__ WFrag, const float* __restrict__ bo,
    float* __restrict__ out){
  int tid = threadIdx.x;
  int lane = tid & 63, wvi = tid >> 6;
  int l31 = lane & 31, h = lane >> 5;
  int blk = blockIdx.x;
  int b = blk >> 8;
  int hw0 = ((blk & 255) << 8) | (wvi << 6);
  size_t base = ((size_t)b) << 22;
  #pragma unroll
  for (int nt=0;nt<2;nt++){
    int px = hw0 | (nt<<5) | l31;
    short8 XH[4], XL[4];
    #pragma unroll
    for (int kt=0;kt<4;kt++){
      float xv[8];
      #pragma unroll
      for (int i=0;i<8;i++){
        int c = (kt<<4) + (h<<2) + (i&3) + ((i>>2)<<3);
        xv[i] = in[base + ((size_t)c<<16) + px];
      }
      short8 fh, fl;
      #pragma unroll
      for (int i=0;i<8;i++){
        short hi = f2bf(xv[i]); fh[i]=hi; fl[i]=f2bf(xv[i]-bf16f(hi));
      }
      XH[kt]=fh; XL[kt]=fl;
    }
    #pragma unroll
    for (int mt=0;mt<2;mt++){
      f32x16 acc;
      #pragma unroll
      for (int r=0;r<16;r++) acc[r]=0.f;
      __builtin_amdgcn_s_setprio(1);
      #pragma unroll
      for (int kt=0;kt<4;kt++){
        short8 WAh = *(const short8*)&WFrag[WFofs(2,0,mt,kt) + (lane<<3)];
        short8 WAl = *(const short8*)&WFrag[WFofs(2,1,mt,kt) + (lane<<3)];
        acc = __builtin_amdgcn_mfma_f32_32x32x16_bf16(WAh, XH[kt], acc, 0,0,0);
        acc = __builtin_amdgcn_mfma_f32_32x32x16_bf16(WAh, XL[kt], acc, 0,0,0);
        acc = __builtin_amdgcn_mfma_f32_32x32x16_bf16(WAl, XH[kt], acc, 0,0,0);
      }
      __builtin_amdgcn_s_setprio(0);
      #pragma unroll
      for (int rr=0;rr<4;rr++){
        float4 b4 = *(const float4*)&bo[(mt<<5)+(rr<<3)+(h<<2)];
        #pragma unroll
        for (int t=0;t<4;t++){
          int oc = (mt<<5) + (rr<<3) + (h<<2) + t;
          float bb = (t==0)?b4.x:(t==1)?b4.y:(t==2)?b4.z:b4.w;
          out[base + ((size_t)oc<<16) + px] = acc[4*rr+t] + bb;
        }
      }
    }
  }
}

extern "C" void kernel_launch(void* const* d_in, const int* in_sizes, int n_in,
                              void* d_out, int out_size, void* d_ws, size_t ws_size,
                              hipStream_t stream) {
  const float* x    = (const float*)d_in[0];
  const float* Wv   = (const float*)d_in[1];
  const float* bv   = (const float*)d_in[2];
  const float* Wri  = (const float*)d_in[3];
  const float* bri  = (const float*)d_in[4];
  const float* Wrc  = (const float*)d_in[5];
  const float* brc  = (const float*)d_in[6];
  const float* ln_w = (const float*)d_in[7];
  const float* ln_b = (const float*)d_in[8];
  const float* Wca  = (const float*)d_in[9];
  const float* bca  = (const float*)d_in[10];
  const float* Wsa  = (const float*)d_in[11];
  const float* bsa  = (const float*)d_in[12];
  const float* Wm1  = (const float*)d_in[13];
  const float* bm1  = (const float*)d_in[14];
  const float* Wm2  = (const float*)d_in[15];
  const float* bm2  = (const float*)d_in[16];
  const float* Wq   = (const float*)d_in[17];
  const float* bq   = (const float*)d_in[18];
  const float* Wk   = (const float*)d_in[19];
  const float* bk   = (const float*)d_in[20];
  const float* Wd1  = (const float*)d_in[21];
  const float* bd1  = (const float*)d_in[22];
  const float* Wd2  = (const float*)d_in[23];
  const float* bd2  = (const float*)d_in[24];
  const float* Wo   = (const float*)d_in[25];
  const float* bo   = (const float*)d_in[26];
  float* out = (float*)d_out;

  float* ws = (float*)d_ws;
  float* v_buf   = ws;                    // 16777216
  float* out_buf = v_buf + 16777216;      // 16777216
  float* x_buf   = out_buf + 16777216;    // 4194304
  float* xm_buf  = x_buf + 4194304;       // 262144
  float* sa_buf  = xm_buf + 262144;       // 262144
  float* bsum    = sa_buf + 262144;       // 32768 (2048 blocks x 16)
  float* ca_buf  = bsum + 32768;          // 256
  float* var_buf = ca_buf + 256;          // 4096
  float* sel_buf = var_buf + 4096;        // 4096
  float* mrow1   = sel_buf + 4096;        // 2048
  float* mrow0   = mrow1 + 2048;          // 2048
  float* mask1   = mrow0 + 2048;          // 4096
  float* mask0   = mask1 + 4096;          // 4096
  float* mask1T  = mask0 + 4096;          // 4096
  float* mask0T  = mask1T + 4096;         // 4096
  float* WriE    = mask0T + 4096;         // 1024
  float* WrcE    = WriE + 1024;           // 1024
  float* briE    = WrcE + 1024;           // 16
  float* brcE    = briE + 16;             // 16
  short* WFrag   = (short*)(brcE + 16);   // 49152 shorts (24576 float slots)
  float* dw_buf  = v_buf;                 // reuse: v dead after k6

  k0_combine<<<4,256,0,stream>>>(Wv,bv,Wri,bri,Wrc,brc,WriE,briE,WrcE,brcE);
  k_prep<<<24,256,0,stream>>>(Wq,Wk,Wo,Wv,WriE,WrcE,WFrag);
  k_premask1<<<2048,256,0,stream>>>(Wm1,bm1,mrow1,mrow0);
  k_premask2<<<4096,256,0,stream>>>(Wm2,bm2,mrow1,mrow0,mask1,mask0,mask1T,mask0T);
  k1_pw<<<2048,256,0,stream>>>(x,WFrag,bv,briE,brcE,ln_w,ln_b,v_buf,x_buf,xm_buf,bsum);
  k2_sa<<<1024,256,0,stream>>>(x_buf,Wsa,bsa,sa_buf);
  k3_ca<<<1,256,0,stream>>>(bsum,Wca,bca,ca_buf);
  k4a_var<<<16,256,0,stream>>>(xm_buf,var_buf);
  k4b_sel<<<4,1024,0,stream>>>(var_buf,sel_buf);
  k6_attn<<<2048,256,0,stream>>>(x,v_buf,sa_buf,sel_buf,mask1,mask0,mask1T,mask0T,WFrag,bq,bk,out_buf);
  k7_fused<<<16384,256,0,stream>>>(out_buf,Wd1,bd1,Wd2,bd2,ca_buf,dw_buf);
  k7c_proj<<<1024,256,0,stream>>>(dw_buf,WFrag,bo,out);
}

// Round 20
// 328.449 us; speedup vs baseline: 1.0092x; 1.0092x over previous
//
#include <hip/hip_runtime.h>
#include <hip/hip_bf16.h>
#include <math.h>

typedef __attribute__((ext_vector_type(8))) short short8;
typedef __attribute__((ext_vector_type(16))) float f32x16;

__device__ __forceinline__ float lrelu(float x){ return x >= 0.f ? x : 0.1f*x; }
__device__ __forceinline__ float sigmoidf(float x){ return 1.f/(1.f+expf(-x)); }
__device__ __forceinline__ short f2bf(float f){
  __hip_bfloat16 hb = __float2bfloat16(f);
  return *reinterpret_cast<short*>(&hb);
}
__device__ __forceinline__ float bf16f(short s){
  return __uint_as_float(((unsigned)(unsigned short)s)<<16);
}

// WFrag frag index: (((w*2+part)*2+mt)*4+kt)*512 + lane*8
// w: 0=Wq 1=Wk 2=Wo (mt=0,1) | 3=Wv[0:32] 4=Wv[32:64] 5=WriE|WrcE (mt=0 only)
__device__ __forceinline__ int WFofs(int w,int part,int mt,int kt){
  return (((w*2+part)*2+mt)*4+kt)*512;
}

// ---------- K0: effective weights WriE = Wri@Wv, WrcE = Wrc@Wv, biases ----------
__global__ void k0_combine(const float* __restrict__ Wv, const float* __restrict__ bv,
                           const float* __restrict__ Wri, const float* __restrict__ bri,
                           const float* __restrict__ Wrc, const float* __restrict__ brc,
                           float* __restrict__ WriE, float* __restrict__ briE,
                           float* __restrict__ WrcE, float* __restrict__ brcE){
  int idx = blockIdx.x*256 + threadIdx.x;
  if (idx < 1024){
    int j = idx>>6, c = idx&63;
    float s1=0.f, s2=0.f;
    for (int k=0;k<64;k++){ s1 = fmaf(Wri[j*64+k], Wv[k*64+c], s1); s2 = fmaf(Wrc[j*64+k], Wv[k*64+c], s2); }
    WriE[idx]=s1; WrcE[idx]=s2;
  }
  if (idx < 16){
    float s1=bri[idx], s2=brc[idx];
    for (int k=0;k<64;k++){ s1 = fmaf(Wri[idx*64+k], bv[k], s1); s2 = fmaf(Wrc[idx*64+k], bv[k], s2); }
    briE[idx]=s1; brcE[idx]=s2;
  }
}

// ---------- prep: MFMA W-frag blob (Wq/Wk/Wo/Wv/Wri|Wrc, hi/lo) ----------
__global__ void k_prep(const float* __restrict__ Wq, const float* __restrict__ Wk,
                       const float* __restrict__ Wo, const float* __restrict__ Wv,
                       const float* __restrict__ WriE, const float* __restrict__ WrcE,
                       short* __restrict__ WFrag){
  int idx = blockIdx.x*256 + threadIdx.x;
  if (idx < 6144){
    int w = idx>>10, rem = idx&1023;
    int part = rem>>9, mt = (rem>>8)&1, kt = (rem>>6)&3, lane = rem&63;
    int hh = lane>>5;
    short8 frag;
    #pragma unroll
    for (int i=0;i<8;i++){
      int kl = (hh<<2) + (i&3) + ((i>>2)<<3);
      int kfull = (kt<<4) + kl;
      float val = 0.f;
      if (w < 3){
        const float* W = (w==0)?Wq:((w==1)?Wk:Wo);
        int j = (mt<<5)|(lane&31);
        val = W[j*64 + kfull];
      } else if (mt == 0){
        int j = lane&31;
        if (w==3)      val = Wv[j*64 + kfull];
        else if (w==4) val = Wv[(32+j)*64 + kfull];
        else           val = (j<16) ? WriE[j*64 + kfull] : WrcE[(j-16)*64 + kfull];
      }
      short hi = f2bf(val);
      frag[i] = part ? f2bf(val - bf16f(hi)) : hi;
    }
    *(short8*)&WFrag[WFofs(w,part,mt,kt) + (lane<<3)] = frag;
  }
}

// ---------- premask 1 ----------
__global__ void k_premask1(const float* __restrict__ Wm1, const float* __restrict__ bm1,
                           float* __restrict__ mrow1, float* __restrict__ mrow0){
  __shared__ float red[256];
  int j = blockIdx.x, tid = threadIdx.x;
  const float* row = Wm1 + (size_t)j*4096;
  float s=0.f;
  for (int e=tid;e<4096;e+=256) s += row[e];
  red[tid]=s; __syncthreads();
  for (int o=128;o;o>>=1){ if (tid<o) red[tid]+=red[tid+o]; __syncthreads(); }
  if (tid==0){
    float t = red[0]+bm1[j];
    mrow1[j] = lrelu(t);
    mrow0[j] = lrelu(bm1[j]);
  }
}

// ---------- premask 2 (+ transposed copies) ----------
__global__ void k_premask2(const float* __restrict__ Wm2, const float* __restrict__ bm2,
                           const float* __restrict__ mrow1, const float* __restrict__ mrow0,
                           float* __restrict__ mask1, float* __restrict__ mask0,
                           float* __restrict__ mask1T, float* __restrict__ mask0T){
  __shared__ float r1[256], r0[256];
  int e = blockIdx.x, tid = threadIdx.x;
  const float* row = Wm2 + (size_t)e*2048;
  float s1=0.f, s0=0.f;
  for (int j=tid;j<2048;j+=256){ float wv=row[j]; s1 = fmaf(wv, mrow1[j], s1); s0 = fmaf(wv, mrow0[j], s0); }
  r1[tid]=s1; r0[tid]=s0; __syncthreads();
  for (int o=128;o;o>>=1){ if (tid<o){ r1[tid]+=r1[tid+o]; r0[tid]+=r0[tid+o]; } __syncthreads(); }
  if (tid==0){
    float m1 = r1[0]+bm2[e], m0 = r0[0]+bm2[e];
    mask1[e]=m1; mask0[e]=m0;
    int p = e>>6, c = e&63;
    mask1T[(c<<6)|p]=m1; mask0T[(c<<6)|p]=m0;
  }
}

// ---------- K1 (MFMA): per-pixel v, xm, x_, block channel-sums ----------
__global__ __launch_bounds__(256, 4) void k1_pw(
    const float* __restrict__ x, const short* __restrict__ WFrag,
    const float* __restrict__ bv,
    const float* __restrict__ briE, const float* __restrict__ brcE,
    const float* __restrict__ ln_w, const float* __restrict__ ln_b,
    float* __restrict__ v, float* __restrict__ x_, float* __restrict__ xm,
    float* __restrict__ bsum){
  __shared__ float wred[4][16];
  int tid = threadIdx.x, lane = tid&63, wvi = tid>>6, l31 = lane&31, h = lane>>5;
  int blk = blockIdx.x;
  int b = blk>>9;
  int hw = ((blk&511)<<7) | (wvi<<5) | l31;
  size_t xb = (((size_t)b)<<22) + hw;
  short8 XH[4], XL[4];
  #pragma unroll
  for (int kt=0;kt<4;kt++){
    float xv[8];
    #pragma unroll
    for (int i=0;i<8;i++){
      int c = (kt<<4) + (h<<2) + (i&3) + ((i>>2)<<3);
      xv[i] = x[xb + ((size_t)c<<16)];
    }
    short8 fh, fl;
    #pragma unroll
    for (int i=0;i<8;i++){ short hi=f2bf(xv[i]); fh[i]=hi; fl[i]=f2bf(xv[i]-bf16f(hi)); }
    XH[kt]=fh; XL[kt]=fl;
  }
  f32x16 T[3];
  #pragma unroll
  for (int t3=0;t3<3;t3++){
    f32x16 acc;
    #pragma unroll
    for (int r=0;r<16;r++) acc[r]=0.f;
    #pragma unroll
    for (int kt=0;kt<4;kt++){
      short8 WAh = *(const short8*)&WFrag[WFofs(3+t3,0,0,kt) + (lane<<3)];
      short8 WAl = *(const short8*)&WFrag[WFofs(3+t3,1,0,kt) + (lane<<3)];
      acc = __builtin_amdgcn_mfma_f32_32x32x16_bf16(WAh, XH[kt], acc, 0,0,0);
      acc = __builtin_amdgcn_mfma_f32_32x32x16_bf16(WAh, XL[kt], acc, 0,0,0);
      acc = __builtin_amdgcn_mfma_f32_32x32x16_bf16(WAl, XH[kt], acc, 0,0,0);
    }
    T[t3]=acc;
  }
  #pragma unroll
  for (int r=0;r<16;r++){
    int c0 = (r&3) + ((r>>2)<<3) + (h<<2);
    v[xb + ((size_t)c0<<16)]      = T[0][r] + bv[c0];
    v[xb + ((size_t)(c0+32)<<16)] = T[1][r] + bv[c0+32];
  }
  float s1 = 0.f;
  #pragma unroll
  for (int r=0;r<8;r++){
    int j = (r&3) + ((r>>2)<<3) + (h<<2);
    s1 += lrelu(T[2][r] + briE[j]);
  }
  s1 += __shfl_xor(s1, 32);
  xm[(((size_t)b)<<16) + hw] = s1*(1.f/16.f);
  float vals[8], u = 0.f;
  #pragma unroll
  for (int r=0;r<8;r++){
    int j = (r&3) + ((r>>2)<<3) + (h<<2);
    float t = T[2][8+r] + brcE[j];
    vals[r]=t; u += t;
  }
  u += __shfl_xor(u, 32);
  u *= (1.f/16.f);
  float s2 = 0.f;
  #pragma unroll
  for (int r=0;r<8;r++){ float d = vals[r]-u; s2 += d*d; }
  s2 += __shfl_xor(s2, 32);
  float inv = 1.0f / sqrtf(s2*(1.f/16.f) + 1e-6f);
  float bs[8];
  #pragma unroll
  for (int r=0;r<8;r++){
    int j = (r&3) + ((r>>2)<<3) + (h<<2);
    float t = lrelu((vals[r]-u)*inv*ln_w[j] + ln_b[j]);
    x_[(((size_t)(b*16+j))<<16) + hw] = t;
    bs[r]=t;
  }
  #pragma unroll
  for (int r=0;r<8;r++){
    float val = bs[r];
    val += __shfl_xor(val,1); val += __shfl_xor(val,2); val += __shfl_xor(val,4);
    val += __shfl_xor(val,8); val += __shfl_xor(val,16);
    bs[r]=val;
  }
  if (l31==0){
    #pragma unroll
    for (int r=0;r<8;r++){
      int j = (r&3) + ((r>>2)<<3) + (h<<2);
      wred[wvi][j] = bs[r];
    }
  }
  __syncthreads();
  if (tid<16) bsum[blk*16+tid] = wred[0][tid]+wred[1][tid]+wred[2][tid]+wred[3][tid];
}

// ---------- K2: sa (LDS-tiled 16ch x 18x18) ----------
__global__ __launch_bounds__(256) void k2_sa(const float* __restrict__ x_,
    const float* __restrict__ Wsa, const float* __restrict__ bsa, float* __restrict__ sa){
  __shared__ float T[16*324];
  int blk = blockIdx.x;
  int b = blk>>8;
  int tile = blk&255;
  int x0 = (tile&15)<<4, y0 = (tile>>4)<<4;
  int tid = threadIdx.x;
  for (int e=tid; e<5184; e+=256){
    int ch = e/324, rem = e-ch*324, r = rem/18, cc = rem-r*18;
    int y = y0+r-1, xx = x0+cc-1;
    float v = 0.f;
    if ((unsigned)y<256u && (unsigned)xx<256u) v = x_[(((size_t)(b*16+ch))<<16)+(y<<8)+xx];
    T[e] = v;
  }
  __syncthreads();
  int px = tid&15, py = tid>>4;
  float acc = bsa[0];
  #pragma unroll
  for (int ch=0; ch<16; ch++){
    const float* Tc = T + ch*324 + py*18 + px;
    #pragma unroll
    for (int ky=0;ky<3;ky++)
      #pragma unroll
      for (int kx=0;kx<3;kx++)
        acc = fmaf(Wsa[ch*9+ky*3+kx], Tc[ky*18+kx], acc);
  }
  sa[(((size_t)b)<<16) + ((y0+py)<<8) + x0+px] = sigmoidf(acc);
}

// ---------- K3: ca ----------
__global__ void k3_ca(const float* __restrict__ bsum, const float* __restrict__ Wca,
                      const float* __restrict__ bca, float* __restrict__ ca){
  __shared__ float meanx[4][16];
  int tid = threadIdx.x;
  if (tid < 64){
    int b = tid>>4, j = tid&15;
    float s=0.f;
    for (int blk=0;blk<512;blk++) s += bsum[(b*512+blk)*16 + j];
    meanx[b][j] = s*(1.f/65536.f);
  }
  __syncthreads();
  int b = tid>>6, oc = tid&63;
  float a = bca[oc];
  #pragma unroll
  for (int j=0;j<16;j++) a = fmaf(Wca[oc*16+j], meanx[b][j], a);
  ca[tid] = sigmoidf(a);
}

// ---------- K4a: per-window variance ----------
__global__ void k4a_var(const float* __restrict__ xm, float* __restrict__ var){
  int t = blockIdx.x*256 + threadIdx.x;
  int b = t>>10, n = t&1023, wh = n>>5, ww = n&31;
  const float* base = xm + (((size_t)b)<<16) + (wh<<11) + (ww<<3);
  float s=0.f;
  #pragma unroll
  for (int dh=0;dh<8;dh++){
    #pragma unroll
    for (int dw=0;dw<8;dw++) s += base[(dh<<8)+dw];
  }
  float mean = s*(1.f/64.f);
  float ss=0.f;
  #pragma unroll
  for (int dh=0;dh<8;dh++){
    #pragma unroll
    for (int dw=0;dw<8;dw++){ float d = base[(dh<<8)+dw]-mean; ss += d*d; }
  }
  var[t] = ss*(1.f/63.f);
}

// ---------- K4b: rank -> sel ----------
__global__ __launch_bounds__(1024) void k4b_sel(const float* __restrict__ var, float* __restrict__ sel){
  __shared__ float vs[1024];
  int b = blockIdx.x, tid = threadIdx.x;
  float mine = var[b*1024+tid];
  vs[tid]=mine; __syncthreads();
  int rank=0;
  for (int j=0;j<1024;j++){
    float o = vs[j];
    rank += (o < mine) || (o == mine && j < tid);
  }
  sel[b*1024+tid] = (rank >= 512) ? 1.f : 0.f;
}

// ---------- K6: 2 waves per window, MFMA bf16 hi/lo, (256,3) + s_setprio (T5) ----------
__global__ __launch_bounds__(256, 3) void k6_attn(
    const float* __restrict__ x, const float* __restrict__ v, const float* __restrict__ sa,
    const float* __restrict__ sel,
    const float* __restrict__ mask1, const float* __restrict__ mask0,
    const float* __restrict__ mask1T, const float* __restrict__ mask0T,
    const short* __restrict__ WFrag,
    const float* __restrict__ bq, const float* __restrict__ bk,
    float* __restrict__ out){
  __shared__ short8 KAlds[2][2][8][64];   // [win][keyhalf][hi0-3|lo4-7][lane]
  int tid = threadIdx.x;
  int lane = tid & 63, wvi = tid >> 6;
  int wi = wvi >> 1, ht = wvi & 1;
  int l31 = lane & 31, h = lane >> 5;
  int bid = blockIdx.x;
  int blk = ((bid & 7) << 8) | (bid >> 3);      // 2048 = 8*256 bijective XCD swizzle
  int wg = (blk << 1) | wi;
  int b = wg >> 10, n = wg & 1023;
  int pix0 = ((n >> 5) << 11) | ((n & 31) << 3);
  bool sel1 = sel[wg] > 0.5f;
  const float* mrow  = sel1 ? mask1  : mask0;
  const float* mrowT = sel1 ? mask1T : mask0T;
  size_t cbase = (((size_t)b) << 22) + pix0;

  int p = (ht<<5) | l31;
  int po = ((p>>3)<<8) | (p&7);
  size_t gp = cbase + po;
  const float* mr = mrow + (p<<6);
  short8 XBh[4], XBl[4];
  #pragma unroll
  for (int kt=0;kt<4;kt++){
    float4 ma = *(const float4*)&mr[(kt<<4)+(h<<2)];
    float4 mb = *(const float4*)&mr[(kt<<4)+(h<<2)+8];
    float xv[8];
    #pragma unroll
    for (int i=0;i<8;i++){
      int c = (kt<<4) + (h<<2) + (i&3) + ((i>>2)<<3);
      xv[i] = x[gp + ((size_t)c<<16)];
    }
    xv[0]*=ma.x; xv[1]*=ma.y; xv[2]*=ma.z; xv[3]*=ma.w;
    xv[4]*=mb.x; xv[5]*=mb.y; xv[6]*=mb.z; xv[7]*=mb.w;
    short8 fh, fl;
    #pragma unroll
    for (int i=0;i<8;i++){
      short hi = f2bf(xv[i]); fh[i]=hi; fl[i]=f2bf(xv[i]-bf16f(hi));
    }
    XBh[kt]=fh; XBl[kt]=fl;
  }

  short8 QBh[4], QBl[4];
  #pragma unroll
  for (int mt=0;mt<2;mt++){
    f32x16 acc;
    #pragma unroll
    for (int r=0;r<16;r++) acc[r]=0.f;
    __builtin_amdgcn_s_setprio(1);
    #pragma unroll
    for (int kt=0;kt<4;kt++){
      short8 WAh = *(const short8*)&WFrag[WFofs(0,0,mt,kt) + (lane<<3)];
      short8 WAl = *(const short8*)&WFrag[WFofs(0,1,mt,kt) + (lane<<3)];
      acc = __builtin_amdgcn_mfma_f32_32x32x16_bf16(WAh, XBh[kt], acc, 0,0,0);
      acc = __builtin_amdgcn_mfma_f32_32x32x16_bf16(WAh, XBl[kt], acc, 0,0,0);
      acc = __builtin_amdgcn_mfma_f32_32x32x16_bf16(WAl, XBh[kt], acc, 0,0,0);
    }
    __builtin_amdgcn_s_setprio(0);
    #pragma unroll
    for (int rr=0;rr<4;rr++){
      float4 b4 = *(const float4*)&bq[(mt<<5)+(rr<<3)+(h<<2)];
      acc[4*rr+0]+=b4.x; acc[4*rr+1]+=b4.y; acc[4*rr+2]+=b4.z; acc[4*rr+3]+=b4.w;
    }
    #pragma unroll
    for (int kk=0;kk<2;kk++){
      short8 fh, fl;
      #pragma unroll
      for (int i=0;i<8;i++){
        float vv = acc[8*kk+i];
        short hi = f2bf(vv); fh[i]=hi; fl[i]=f2bf(vv-bf16f(hi));
      }
      QBh[2*mt+kk]=fh; QBl[2*mt+kk]=fl;
    }
  }

  #pragma unroll
  for (int mt=0;mt<2;mt++){
    f32x16 acc;
    #pragma unroll
    for (int r=0;r<16;r++) acc[r]=0.f;
    __builtin_amdgcn_s_setprio(1);
    #pragma unroll
    for (int kt=0;kt<4;kt++){
      short8 WAh = *(const short8*)&WFrag[WFofs(1,0,mt,kt) + (lane<<3)];
      short8 WAl = *(const short8*)&WFrag[WFofs(1,1,mt,kt) + (lane<<3)];
      acc = __builtin_amdgcn_mfma_f32_32x32x16_bf16(WAh, XBh[kt], acc, 0,0,0);
      acc = __builtin_amdgcn_mfma_f32_32x32x16_bf16(WAh, XBl[kt], acc, 0,0,0);
      acc = __builtin_amdgcn_mfma_f32_32x32x16_bf16(WAl, XBh[kt], acc, 0,0,0);
    }
    __builtin_amdgcn_s_setprio(0);
    #pragma unroll
    for (int rr=0;rr<4;rr++){
      float4 b4 = *(const float4*)&bk[(mt<<5)+(rr<<3)+(h<<2)];
      acc[4*rr+0]+=b4.x; acc[4*rr+1]+=b4.y; acc[4*rr+2]+=b4.z; acc[4*rr+3]+=b4.w;
    }
    #pragma unroll
    for (int kk=0;kk<2;kk++){
      short8 fh, fl;
      #pragma unroll
      for (int i=0;i<8;i++){
        float vv = acc[8*kk+i];
        short hi = f2bf(vv); fh[i]=hi; fl[i]=f2bf(vv-bf16f(hi));
      }
      KAlds[wi][ht][2*mt+kk][lane]   = fh;
      KAlds[wi][ht][4+2*mt+kk][lane] = fl;
    }
  }
  __syncthreads();

  f32x16 ST[2];
  #pragma unroll
  for (int mt=0;mt<2;mt++){
    f32x16 acc;
    #pragma unroll
    for (int r=0;r<16;r++) acc[r]=0.f;
    __builtin_amdgcn_s_setprio(1);
    #pragma unroll
    for (int kt=0;kt<4;kt++){
      short8 kh = KAlds[wi][mt][kt][lane];
      short8 kl = KAlds[wi][mt][4+kt][lane];
      acc = __builtin_amdgcn_mfma_f32_32x32x16_bf16(kh, QBh[kt], acc, 0,0,0);
      acc = __builtin_amdgcn_mfma_f32_32x32x16_bf16(kh, QBl[kt], acc, 0,0,0);
      acc = __builtin_amdgcn_mfma_f32_32x32x16_bf16(kl, QBh[kt], acc, 0,0,0);
    }
    __builtin_amdgcn_s_setprio(0);
    ST[mt] = acc;
  }

  float mx = ST[0][0];
  #pragma unroll
  for (int r=1;r<16;r++) mx = fmaxf(mx, ST[0][r]);
  #pragma unroll
  for (int r=0;r<16;r++) mx = fmaxf(mx, ST[1][r]);
  mx = fmaxf(mx, __shfl_xor(mx, 32));
  float sum = 0.f;
  #pragma unroll
  for (int mt=0;mt<2;mt++)
    #pragma unroll
    for (int r=0;r<16;r++){ float e = expf(ST[mt][r]-mx); ST[mt][r]=e; sum += e; }
  sum += __shfl_xor(sum, 32);
  float inv = 1.f/sum;

  short8 PB[4];
  #pragma unroll
  for (int mt=0;mt<2;mt++)
    #pragma unroll
    for (int kk=0;kk<2;kk++){
      short8 f;
      #pragma unroll
      for (int i=0;i<8;i++) f[i] = f2bf(ST[mt][8*kk+i]*inv);
      PB[2*mt+kk]=f;
    }

  float sav = sa[(((size_t)b)<<16) + pix0 + po];

  #pragma unroll
  for (int mtc=0;mtc<2;mtc++){
    int c0 = (mtc<<5);
    int cl = c0 | l31;
    const float* vp = v + cbase + ((size_t)cl<<16);
    const float* mTr = mrowT + (cl<<6);
    f32x16 acc;
    #pragma unroll
    for (int r=0;r<16;r++) acc[r]=0.f;
    __builtin_amdgcn_s_setprio(1);
    #pragma unroll
    for (int kt=0;kt<4;kt++){
      float4 va  = *(const float4*)&vp[((kt<<1)<<8) + (h<<2)];
      float4 vb2 = *(const float4*)&vp[(((kt<<1)|1)<<8) + (h<<2)];
      float4 ma = *(const float4*)&mTr[(kt<<4)+(h<<2)];
      float4 mb = *(const float4*)&mTr[(kt<<4)+(h<<2)+8];
      short8 f;
      f[0]=f2bf(va.x*ma.x); f[1]=f2bf(va.y*ma.y); f[2]=f2bf(va.z*ma.z); f[3]=f2bf(va.w*ma.w);
      f[4]=f2bf(vb2.x*mb.x); f[5]=f2bf(vb2.y*mb.y); f[6]=f2bf(vb2.z*mb.z); f[7]=f2bf(vb2.w*mb.w);
      acc = __builtin_amdgcn_mfma_f32_32x32x16_bf16(f, PB[kt], acc, 0,0,0);
    }
    __builtin_amdgcn_s_setprio(0);
    #pragma unroll
    for (int rr=0;rr<4;rr++){
      float4 m4 = *(const float4*)&mr[c0+(rr<<3)+(h<<2)];
      #pragma unroll
      for (int t=0;t<4;t++){
        int c = c0 + (rr<<3) + (h<<2) + t;
        size_t g = cbase + ((size_t)c<<16) + po;
        float vv = v[g];
        float mm = (t==0)?m4.x:(t==1)?m4.y:(t==2)?m4.z:m4.w;
        out[g] = acc[4*rr+t] + sav*vv*(1.f-mm);
      }
    }
  }
}

// ---------- K7: fused dw3x3(pad1) -> dw3x3(dil2,pad2) -> gelu*ca + residual (32x32 tiles) ----------
__global__ __launch_bounds__(256) void k7_fused(const float* __restrict__ in,
    const float* __restrict__ Wd1, const float* __restrict__ bd1,
    const float* __restrict__ Wd2, const float* __restrict__ bd2,
    const float* __restrict__ ca, float* __restrict__ dwout){
  __shared__ float IN[38*39];
  __shared__ float C1[36*37];
  int blk = blockIdx.x;
  int tile = blk & 63;
  int tx = tile & 7, ty = tile >> 3;
  int ch = (blk>>6) & 63, b = blk>>12;
  int x0 = tx<<5, y0 = ty<<5;
  const float* plane = in + (((size_t)(b*64+ch))<<16);
  int tid = threadIdx.x;
  for (int e = tid; e < 1444; e += 256){
    int r = e/38, cc = e - r*38;
    int y = y0 + r - 3, xx = x0 + cc - 3;
    float vv = 0.f;
    if ((unsigned)y < 256u && (unsigned)xx < 256u) vv = plane[(y<<8)+xx];
    IN[r*39+cc] = vv;
  }
  __syncthreads();
  float w1[9], w2[9];
  #pragma unroll
  for (int t=0;t<9;t++){ w1[t]=Wd1[ch*9+t]; w2[t]=Wd2[ch*9+t]; }
  float b1 = bd1[ch];
  for (int e = tid; e < 1296; e += 256){
    int r = e/36, cc = e - r*36;
    int yc1 = y0 + r - 2, xc1 = x0 + cc - 2;
    float acc = 0.f;
    if ((unsigned)yc1 < 256u && (unsigned)xc1 < 256u){
      acc = b1;
      #pragma unroll
      for (int ky=0;ky<3;ky++)
        #pragma unroll
        for (int kx=0;kx<3;kx++)
          acc = fmaf(w1[ky*3+kx], IN[(r+ky)*39 + cc+kx], acc);
    }
    C1[r*37+cc] = acc;
  }
  __syncthreads();
  int px = tid & 31, py0 = tid >> 5;
  float cav = ca[b*64+ch];
  float b2 = bd2[ch];
  #pragma unroll
  for (int q=0;q<4;q++){
    int py = py0 + (q<<3);
    float acc = b2;
    #pragma unroll
    for (int ky=0;ky<3;ky++)
      #pragma unroll
      for (int kx=0;kx<3;kx++)
        acc = fmaf(w2[ky*3+kx], C1[(py+2*ky)*37 + px+2*kx], acc);
    float g = 0.5f*acc*(1.f + erff(acc*0.70710678118654752f));
    float resid = IN[(py+3)*39 + px+3];
    size_t o = (((size_t)(b*64+ch))<<16) + ((size_t)((y0+py)<<8)) + x0+px;
    dwout[o] = fmaf(g, cav, resid);
  }
}

// ---------- K7c: final 1x1 conv via MFMA (hi/lo 3-product) ----------
__global__ __launch_bounds__(256, 3) void k7c_proj(const float* __restrict__ in,
    const short* __restrict__ WFrag, const float* __restrict__ bo,
    float* __restrict__ out){
  int tid = threadIdx.x;
  int lane = tid & 63, wvi = tid >> 6;
  int l31 = lane & 31, h = lane >> 5;
  int blk = blockIdx.x;
  int b = blk >> 8;
  int hw0 = ((blk & 255) << 8) | (wvi << 6);
  size_t base = ((size_t)b) << 22;
  #pragma unroll
  for (int nt=0;nt<2;nt++){
    int px = hw0 | (nt<<5) | l31;
    short8 XH[4], XL[4];
    #pragma unroll
    for (int kt=0;kt<4;kt++){
      float xv[8];
      #pragma unroll
      for (int i=0;i<8;i++){
        int c = (kt<<4) + (h<<2) + (i&3) + ((i>>2)<<3);
        xv[i] = in[base + ((size_t)c<<16) + px];
      }
      short8 fh, fl;
      #pragma unroll
      for (int i=0;i<8;i++){
        short hi = f2bf(xv[i]); fh[i]=hi; fl[i]=f2bf(xv[i]-bf16f(hi));
      }
      XH[kt]=fh; XL[kt]=fl;
    }
    #pragma unroll
    for (int mt=0;mt<2;mt++){
      f32x16 acc;
      #pragma unroll
      for (int r=0;r<16;r++) acc[r]=0.f;
      #pragma unroll
      for (int kt=0;kt<4;kt++){
        short8 WAh = *(const short8*)&WFrag[WFofs(2,0,mt,kt) + (lane<<3)];
        short8 WAl = *(const short8*)&WFrag[WFofs(2,1,mt,kt) + (lane<<3)];
        acc = __builtin_amdgcn_mfma_f32_32x32x16_bf16(WAh, XH[kt], acc, 0,0,0);
        acc = __builtin_amdgcn_mfma_f32_32x32x16_bf16(WAh, XL[kt], acc, 0,0,0);
        acc = __builtin_amdgcn_mfma_f32_32x32x16_bf16(WAl, XH[kt], acc, 0,0,0);
      }
      #pragma unroll
      for (int rr=0;rr<4;rr++){
        float4 b4 = *(const float4*)&bo[(mt<<5)+(rr<<3)+(h<<2)];
        #pragma unroll
        for (int t=0;t<4;t++){
          int oc = (mt<<5) + (rr<<3) + (h<<2) + t;
          float bb = (t==0)?b4.x:(t==1)?b4.y:(t==2)?b4.z:b4.w;
          out[base + ((size_t)oc<<16) + px] = acc[4*rr+t] + bb;
        }
      }
    }
  }
}

extern "C" void kernel_launch(void* const* d_in, const int* in_sizes, int n_in,
                              void* d_out, int out_size, void* d_ws, size_t ws_size,
                              hipStream_t stream) {
  const float* x    = (const float*)d_in[0];
  const float* Wv   = (const float*)d_in[1];
  const float* bv   = (const float*)d_in[2];
  const float* Wri  = (const float*)d_in[3];
  const float* bri  = (const float*)d_in[4];
  const float* Wrc  = (const float*)d_in[5];
  const float* brc  = (const float*)d_in[6];
  const float* ln_w = (const float*)d_in[7];
  const float* ln_b = (const float*)d_in[8];
  const float* Wca  = (const float*)d_in[9];
  const float* bca  = (const float*)d_in[10];
  const float* Wsa  = (const float*)d_in[11];
  const float* bsa  = (const float*)d_in[12];
  const float* Wm1  = (const float*)d_in[13];
  const float* bm1  = (const float*)d_in[14];
  const float* Wm2  = (const float*)d_in[15];
  const float* bm2  = (const float*)d_in[16];
  const float* Wq   = (const float*)d_in[17];
  const float* bq   = (const float*)d_in[18];
  const float* Wk   = (const float*)d_in[19];
  const float* bk   = (const float*)d_in[20];
  const float* Wd1  = (const float*)d_in[21];
  const float* bd1  = (const float*)d_in[22];
  const float* Wd2  = (const float*)d_in[23];
  const float* bd2  = (const float*)d_in[24];
  const float* Wo   = (const float*)d_in[25];
  const float* bo   = (const float*)d_in[26];
  float* out = (float*)d_out;

  float* ws = (float*)d_ws;
  float* v_buf   = ws;                    // 16777216
  float* out_buf = v_buf + 16777216;      // 16777216
  float* x_buf   = out_buf + 16777216;    // 4194304
  float* xm_buf  = x_buf + 4194304;       // 262144
  float* sa_buf  = xm_buf + 262144;       // 262144
  float* bsum    = sa_buf + 262144;       // 32768 (2048 blocks x 16)
  float* ca_buf  = bsum + 32768;          // 256
  float* var_buf = ca_buf + 256;          // 4096
  float* sel_buf = var_buf + 4096;        // 4096
  float* mrow1   = sel_buf + 4096;        // 2048
  float* mrow0   = mrow1 + 2048;          // 2048
  float* mask1   = mrow0 + 2048;          // 4096
  float* mask0   = mask1 + 4096;          // 4096
  float* mask1T  = mask0 + 4096;          // 4096
  float* mask0T  = mask1T + 4096;         // 4096
  float* WriE    = mask0T + 4096;         // 1024
  float* WrcE    = WriE + 1024;           // 1024
  float* briE    = WrcE + 1024;           // 16
  float* brcE    = briE + 16;             // 16
  short* WFrag   = (short*)(brcE + 16);   // 49152 shorts (24576 float slots)
  float* dw_buf  = v_buf;                 // reuse: v dead after k6

  k0_combine<<<4,256,0,stream>>>(Wv,bv,Wri,bri,Wrc,brc,WriE,briE,WrcE,brcE);
  k_prep<<<24,256,0,stream>>>(Wq,Wk,Wo,Wv,WriE,WrcE,WFrag);
  k_premask1<<<2048,256,0,stream>>>(Wm1,bm1,mrow1,mrow0);
  k_premask2<<<4096,256,0,stream>>>(Wm2,bm2,mrow1,mrow0,mask1,mask0,mask1T,mask0T);
  k1_pw<<<2048,256,0,stream>>>(x,WFrag,bv,briE,brcE,ln_w,ln_b,v_buf,x_buf,xm_buf,bsum);
  k2_sa<<<1024,256,0,stream>>>(x_buf,Wsa,bsa,sa_buf);
  k3_ca<<<1,256,0,stream>>>(bsum,Wca,bca,ca_buf);
  k4a_var<<<16,256,0,stream>>>(xm_buf,var_buf);
  k4b_sel<<<4,1024,0,stream>>>(var_buf,sel_buf);
  k6_attn<<<2048,256,0,stream>>>(x,v_buf,sa_buf,sel_buf,mask1,mask0,mask1T,mask0T,WFrag,bq,bk,out_buf);
  k7_fused<<<16384,256,0,stream>>>(out_buf,Wd1,bd1,Wd2,bd2,ca_buf,dw_buf);
  k7c_proj<<<1024,256,0,stream>>>(dw_buf,WFrag,bo,out);
}